// Round 1
// baseline (542.243 us; speedup 1.0000x reference)
//
#include <hip/hip_runtime.h>
#include <cstdint>
#include <cstddef>

// ---------- constants ----------
#define BATCH 2
#define CTX 2048
#define EMB 2048
#define NH 16
#define NG 4
#define HD 128
#define NQK (EMB + 2*NG*HD)   // 3072 combined QKV output cols
#define MROWS (BATCH*CTX)     // 4096

typedef __bf16 bf16x8 __attribute__((ext_vector_type(8)));
typedef float  f32x4  __attribute__((ext_vector_type(4)));

__device__ __forceinline__ ushort f2bf(float f) {
    uint32_t u = __float_as_uint(f);
    u += 0x7FFFu + ((u >> 16) & 1u);   // round-to-nearest-even
    return (ushort)(u >> 16);
}

__device__ __forceinline__ void gload_lds16(const void* g, void* l) {
    __builtin_amdgcn_global_load_lds((const __attribute__((address_space(1))) void*)g,
                                     (__attribute__((address_space(3))) void*)l, 16, 0, 0);
}

// ---------- sin table: sintab[pos][j], j in 0..63 ----------
__global__ __launch_bounds__(256) void k_sintab(float* __restrict__ sintab) {
    int t = blockIdx.x * 256 + threadIdx.x;   // 2048*64
    int j = t & 63, p = t >> 6;
    float theta = 1.0f / powf(10000.0f, (float)(2 * j) / 64.0f);
    sintab[t] = sinf((float)p * theta);
}

// ---------- f32 -> bf16 elementwise (4 per thread) ----------
__global__ __launch_bounds__(256) void k_cvt(const float4* __restrict__ src, ushort4* __restrict__ dst) {
    int i = blockIdx.x * 256 + threadIdx.x;
    float4 v = src[i];
    ushort4 o;
    o.x = f2bf(v.x); o.y = f2bf(v.y); o.z = f2bf(v.z); o.w = f2bf(v.w);
    dst[i] = o;
}

// ---------- tiled transpose f32[R][C] -> bf16 dst[C][R] ----------
__global__ __launch_bounds__(256) void k_transpose_cvt(const float* __restrict__ src, int src_ld,
                                                       ushort* __restrict__ dst, int dst_ld) {
    __shared__ float tile[32][33];
    int tx = threadIdx.x, ty = threadIdx.y;          // 32 x 8
    int c0 = blockIdx.x * 32, r0 = blockIdx.y * 32;
    #pragma unroll
    for (int i = 0; i < 4; ++i)
        tile[ty + i*8][tx] = src[(size_t)(r0 + ty + i*8) * src_ld + c0 + tx];
    __syncthreads();
    #pragma unroll
    for (int i = 0; i < 4; ++i)
        dst[(size_t)(c0 + ty + i*8) * dst_ld + r0 + tx] = f2bf(tile[tx][ty + i*8]);
}

// ---------- RoPE + convert: qkv f32 [4096][ld] cols [co..co+nh*128) -> out [B][nh][CTX][128] bf16 ----------
__global__ __launch_bounds__(256) void k_rope_cvt(const float* __restrict__ qkv, int ld, int co, int nh,
                                                  const float* __restrict__ sintab, ushort* __restrict__ out) {
    int t = blockIdx.x * 256 + threadIdx.x;   // BATCH*nh*CTX*64
    int j = t & 63;
    int rest = t >> 6;
    int pos = rest & (CTX - 1);
    int rest2 = rest >> 11;
    int hh = rest2 % nh;
    int b = rest2 / nh;
    const float* base = qkv + (size_t)(b * CTX + pos) * ld + co + hh * HD;
    float a = base[j];
    float bb = base[j + 64];
    float sv = sintab[pos * 64 + j];
    ushort* ob = out + ((size_t)((b * nh + hh) * CTX + pos)) * HD;
    ob[j]      = f2bf((a - bb) * sv);
    ob[j + 64] = f2bf((bb + a) * sv);
}

// ---------- GEMM: C[M][N] (f32) = A[M][K] (bf16) x Bt[N][K] (bf16), optional bias ----------
// 128x128 tile, BK=32, 256 threads = 4 waves, wave computes 64x64.
__global__ __launch_bounds__(256) void k_gemm_bt(const ushort* __restrict__ A, const ushort* __restrict__ Bt,
                                                 float* __restrict__ C, int M, int N, int K,
                                                 const float* __restrict__ bias) {
    __shared__ __align__(16) ushort As[128 * 32];
    __shared__ __align__(16) ushort Bs[128 * 32];
    int tid = threadIdx.x;
    int lane = tid & 63;
    int wave = tid >> 6;
    int wr = wave >> 1, wc = wave & 1;
    int m0 = blockIdx.y * 128, n0 = blockIdx.x * 128;
    int lr = lane & 15, lg = lane >> 4;

    f32x4 acc[4][4] = {};

    int arow = lane >> 2;        // 0..15 within chunk
    int kpart = (lane & 3) * 8;  // 0,8,16,24

    for (int k0 = 0; k0 < K; k0 += 32) {
        #pragma unroll
        for (int s = 0; s < 2; ++s) {
            int c = wave * 2 + s;
            const ushort* ga = A + (size_t)(m0 + c*16 + arow) * K + k0 + kpart;
            gload_lds16(ga, &As[c * 512]);
            const ushort* gb = Bt + (size_t)(n0 + c*16 + arow) * K + k0 + kpart;
            gload_lds16(gb, &Bs[c * 512]);
        }
        __syncthreads();
        bf16x8 af[4], bfr[4];
        #pragma unroll
        for (int mt = 0; mt < 4; ++mt)
            af[mt] = *(const bf16x8*)&As[(wr*64 + mt*16 + lr) * 32 + lg * 8];
        #pragma unroll
        for (int nt = 0; nt < 4; ++nt)
            bfr[nt] = *(const bf16x8*)&Bs[(wc*64 + nt*16 + lr) * 32 + lg * 8];
        #pragma unroll
        for (int mt = 0; mt < 4; ++mt)
            #pragma unroll
            for (int nt = 0; nt < 4; ++nt)
                acc[mt][nt] = __builtin_amdgcn_mfma_f32_16x16x32_bf16(af[mt], bfr[nt], acc[mt][nt], 0, 0, 0);
        __syncthreads();
    }

    #pragma unroll
    for (int mt = 0; mt < 4; ++mt) {
        #pragma unroll
        for (int nt = 0; nt < 4; ++nt) {
            int col = n0 + wc*64 + nt*16 + lr;
            float bv = bias ? bias[col] : 0.0f;
            #pragma unroll
            for (int r = 0; r < 4; ++r) {
                int row = m0 + wr*64 + mt*16 + lg*4 + r;
                C[(size_t)row * N + col] = acc[mt][nt][r] + bv;
            }
        }
    }
}

// ---------- flash attention: 1 wave / block, 16 q-rows / block ----------
// Qb [B][NH][CTX][HD], Kb [B][NG][CTX][HD], Vt [B][NG][HD][CTX]  (bf16)
// y  [B*CTX][NH*HD] bf16
__global__ __launch_bounds__(64) void k_attn(const ushort* __restrict__ Qb, const ushort* __restrict__ Kb,
                                             const ushort* __restrict__ Vt, ushort* __restrict__ y) {
    __shared__ __align__(16) ushort Pl[16][32];
    int lane = threadIdx.x;
    int idx = blockIdx.x;
    int qt = idx & 127;           // CTX/16
    int h  = (idx >> 7) & 15;
    int b  = idx >> 11;
    int g  = h >> 2;
    int q0 = qt * 16;
    int lr = lane & 15, lg = lane >> 4;

    const ushort* qptr = Qb + ((size_t)((b*NH + h) * CTX + q0 + lr)) * HD + lg * 8;
    bf16x8 qf[4];
    #pragma unroll
    for (int c = 0; c < 4; ++c) qf[c] = *(const bf16x8*)(qptr + c * 32);

    f32x4 o[8] = {};
    float m[4], lsum[4];
    #pragma unroll
    for (int r = 0; r < 4; ++r) { m[r] = -INFINITY; lsum[r] = 0.0f; }

    const ushort* kbase = Kb + (size_t)(b*NG + g) * CTX * HD;
    const ushort* vbase = Vt + (size_t)(b*NG + g) * HD * CTX;
    const float scale = 0.08838834764831845f;  // 1/sqrt(128)

    for (int kv0 = 0; kv0 < q0 + 16; kv0 += 32) {
        // S = Q K^T for 32 keys (two 16-key halves)
        f32x4 s[2];
        #pragma unroll
        for (int t = 0; t < 2; ++t) {
            f32x4 sv = {0.f, 0.f, 0.f, 0.f};
            const ushort* kp = kbase + (size_t)(kv0 + t*16 + lr) * HD + lg * 8;
            #pragma unroll
            for (int c = 0; c < 4; ++c) {
                bf16x8 kf = *(const bf16x8*)(kp + c * 32);
                sv = __builtin_amdgcn_mfma_f32_16x16x32_bf16(qf[c], kf, sv, 0, 0, 0);
            }
            s[t] = sv;
        }
        // scale + causal mask
        float pm0[4], pm1[4];
        #pragma unroll
        for (int r = 0; r < 4; ++r) {
            int qrow = q0 + lg*4 + r;
            float v0 = s[0][r] * scale;
            float v1 = s[1][r] * scale;
            if (kv0 + lr > qrow)      v0 = -INFINITY;
            if (kv0 + 16 + lr > qrow) v1 = -INFINITY;
            pm0[r] = v0; pm1[r] = v1;
        }
        // online softmax
        float alpha[4], p0[4], p1[4];
        #pragma unroll
        for (int r = 0; r < 4; ++r) {
            float tm = fmaxf(pm0[r], pm1[r]);
            #pragma unroll
            for (int off = 1; off < 16; off <<= 1) tm = fmaxf(tm, __shfl_xor(tm, off, 64));
            float mnew = fmaxf(m[r], tm);
            alpha[r] = expf(m[r] - mnew);
            p0[r] = expf(pm0[r] - mnew);
            p1[r] = expf(pm1[r] - mnew);
            float rs = p0[r] + p1[r];
            #pragma unroll
            for (int off = 1; off < 16; off <<= 1) rs += __shfl_xor(rs, off, 64);
            lsum[r] = lsum[r] * alpha[r] + rs;
            m[r] = mnew;
        }
        #pragma unroll
        for (int c = 0; c < 8; ++c)
            #pragma unroll
            for (int r = 0; r < 4; ++r) o[c][r] *= alpha[r];

        // P -> LDS (transpose to A-fragment layout)
        __syncthreads();
        #pragma unroll
        for (int r = 0; r < 4; ++r) {
            Pl[lg*4 + r][lr]      = f2bf(p0[r]);
            Pl[lg*4 + r][16 + lr] = f2bf(p1[r]);
        }
        __syncthreads();
        bf16x8 pf = *(const bf16x8*)&Pl[lr][lg * 8];

        // O += P V
        #pragma unroll
        for (int c = 0; c < 8; ++c) {
            bf16x8 vf = *(const bf16x8*)(vbase + (size_t)(c*16 + lr) * CTX + kv0 + lg * 8);
            o[c] = __builtin_amdgcn_mfma_f32_16x16x32_bf16(pf, vf, o[c], 0, 0, 0);
        }
    }

    // epilogue: normalize + store bf16 into y [b*CTX+row][h*HD+col]
    #pragma unroll
    for (int c = 0; c < 8; ++c) {
        int col = h * HD + c*16 + lr;
        #pragma unroll
        for (int r = 0; r < 4; ++r) {
            int row = q0 + lg*4 + r;
            y[((size_t)(b * CTX + row)) * (NH * HD) + col] = f2bf(o[c][r] / lsum[r]);
        }
    }
}

// ---------- workspace layout (bytes) ----------
#define SIN_OFF   ((size_t)0)
#define XB_OFF    ((size_t)524288)
#define WT_OFF    ((size_t)17301504)
#define WOT_OFF   ((size_t)29884416)
#define QKV_OFF   ((size_t)38273024)
#define QB_OFF    ((size_t)88604672)
#define KB_OFF    ((size_t)105381888)
#define VT_OFF    ((size_t)109576192)
#define YB_OFF    ((size_t)113770496)

extern "C" void kernel_launch(void* const* d_in, const int* in_sizes, int n_in,
                              void* d_out, int out_size, void* d_ws, size_t ws_size,
                              hipStream_t stream) {
    const float* x  = (const float*)d_in[0];
    const float* Wq = (const float*)d_in[1];
    const float* Wk = (const float*)d_in[2];
    const float* Wv = (const float*)d_in[3];
    const float* Wo = (const float*)d_in[4];
    const float* bo = (const float*)d_in[5];
    float* out = (float*)d_out;
    char* ws = (char*)d_ws;

    float*  sintab = (float*)(ws + SIN_OFF);
    ushort* xb     = (ushort*)(ws + XB_OFF);
    ushort* Wt     = (ushort*)(ws + WT_OFF);
    ushort* Wot    = (ushort*)(ws + WOT_OFF);
    float*  QKVf   = (float*)(ws + QKV_OFF);
    ushort* Qb     = (ushort*)(ws + QB_OFF);
    ushort* Kb     = (ushort*)(ws + KB_OFF);
    ushort* Vt     = (ushort*)(ws + VT_OFF);
    ushort* yb     = (ushort*)(ws + YB_OFF);

    // 1. sin table
    k_sintab<<<512, 256, 0, stream>>>(sintab);
    // 2. x -> bf16
    k_cvt<<<(MROWS * EMB / 4) / 256, 256, 0, stream>>>((const float4*)x, (ushort4*)xb);
    // 3. weight transposes -> bf16 [N][K]
    dim3 tb(32, 8);
    k_transpose_cvt<<<dim3(EMB/32, EMB/32), tb, 0, stream>>>(Wq, EMB, Wt, EMB);
    k_transpose_cvt<<<dim3((NG*HD)/32, EMB/32), tb, 0, stream>>>(Wk, NG*HD, Wt + (size_t)EMB * EMB, EMB);
    k_transpose_cvt<<<dim3((NG*HD)/32, EMB/32), tb, 0, stream>>>(Wv, NG*HD, Wt + (size_t)(EMB + NG*HD) * EMB, EMB);
    k_transpose_cvt<<<dim3(EMB/32, EMB/32), tb, 0, stream>>>(Wo, EMB, Wot, EMB);
    // 4. QKV = x @ [Wq|Wk|Wv]   (f32 out [4096][3072])
    k_gemm_bt<<<dim3(NQK/128, MROWS/128), 256, 0, stream>>>(xb, Wt, QKVf, MROWS, NQK, EMB, nullptr);
    // 5. RoPE + convert Q,K ; transpose-convert V
    k_rope_cvt<<<(BATCH*NH*CTX*64)/256, 256, 0, stream>>>(QKVf, NQK, 0, NH, sintab, Qb);
    k_rope_cvt<<<(BATCH*NG*CTX*64)/256, 256, 0, stream>>>(QKVf, NQK, EMB, NG, sintab, Kb);
    for (int b = 0; b < BATCH; ++b)
        for (int g = 0; g < NG; ++g) {
            const float* srcv = QKVf + (size_t)b * CTX * NQK + EMB + NG*HD + g*HD;
            ushort* dstv = Vt + (size_t)(b*NG + g) * HD * CTX;
            k_transpose_cvt<<<dim3(HD/32, CTX/32), tb, 0, stream>>>(srcv, NQK, dstv, CTX);
        }
    // 6. attention
    k_attn<<<BATCH * NH * (CTX/16), 64, 0, stream>>>(Qb, Kb, Vt, yb);
    // 7. out = y @ Wo + bo
    k_gemm_bt<<<dim3(EMB/128, MROWS/128), 256, 0, stream>>>(yb, Wot, out, MROWS, EMB, EMB, bo);
}

// Round 2
// 413.774 us; speedup vs baseline: 1.3105x; 1.3105x over previous
//
#include <hip/hip_runtime.h>
#include <hip/hip_bf16.h>
#include <cstdint>
#include <cstddef>

// ---------- constants ----------
#define BATCH 2
#define CTX 2048
#define EMB 2048
#define NH 16
#define NG 4
#define HD 128
#define NQK (EMB + 2*NG*HD)   // 3072 combined QKV output cols
#define MROWS (BATCH*CTX)     // 4096

typedef __bf16 bf16x8 __attribute__((ext_vector_type(8)));
typedef float  f32x4  __attribute__((ext_vector_type(4)));
typedef float  f32x16 __attribute__((ext_vector_type(16)));

__device__ __forceinline__ ushort f2bf(float f) {
    uint32_t u = __float_as_uint(f);
    u += 0x7FFFu + ((u >> 16) & 1u);   // round-to-nearest-even
    return (ushort)(u >> 16);
}

__device__ __forceinline__ uint32_t packbf(float a, float b) {
    ushort lo = __builtin_bit_cast(ushort, (__bf16)a);
    ushort hi = __builtin_bit_cast(ushort, (__bf16)b);
    return (uint32_t)lo | ((uint32_t)hi << 16);
}

__device__ __forceinline__ bf16x8 mkfrag(uint32_t a, uint32_t b, uint32_t c, uint32_t d) {
    union { uint32_t u[4]; bf16x8 v; } z;
    z.u[0] = a; z.u[1] = b; z.u[2] = c; z.u[3] = d;
    return z.v;
}

__device__ __forceinline__ void gload_lds16(const void* g, void* l) {
    __builtin_amdgcn_global_load_lds((const __attribute__((address_space(1))) void*)g,
                                     (__attribute__((address_space(3))) void*)l, 16, 0, 0);
}

// ---------- sin table: sintab[pos][j], j in 0..63 ----------
__global__ __launch_bounds__(256) void k_sintab(float* __restrict__ sintab) {
    int t = blockIdx.x * 256 + threadIdx.x;   // 2048*64
    int j = t & 63, p = t >> 6;
    float theta = 1.0f / powf(10000.0f, (float)(2 * j) / 64.0f);
    sintab[t] = sinf((float)p * theta);
}

// ---------- f32 -> bf16 elementwise (4 per thread) ----------
__global__ __launch_bounds__(256) void k_cvt(const float4* __restrict__ src, ushort4* __restrict__ dst) {
    int i = blockIdx.x * 256 + threadIdx.x;
    float4 v = src[i];
    ushort4 o;
    o.x = f2bf(v.x); o.y = f2bf(v.y); o.z = f2bf(v.z); o.w = f2bf(v.w);
    dst[i] = o;
}

// ---------- tiled transpose f32[R][C] -> bf16 dst[C][R] ----------
__global__ __launch_bounds__(256) void k_transpose_cvt(const float* __restrict__ src, int src_ld,
                                                       ushort* __restrict__ dst, int dst_ld) {
    __shared__ float tile[32][33];
    int tx = threadIdx.x, ty = threadIdx.y;          // 32 x 8
    int c0 = blockIdx.x * 32, r0 = blockIdx.y * 32;
    #pragma unroll
    for (int i = 0; i < 4; ++i)
        tile[ty + i*8][tx] = src[(size_t)(r0 + ty + i*8) * src_ld + c0 + tx];
    __syncthreads();
    #pragma unroll
    for (int i = 0; i < 4; ++i)
        dst[(size_t)(c0 + ty + i*8) * dst_ld + r0 + tx] = f2bf(tile[tx][ty + i*8]);
}

// ---------- RoPE + convert (+ optional scale folded in) ----------
__global__ __launch_bounds__(256) void k_rope_cvt(const float* __restrict__ qkv, int ld, int co, int nh,
                                                  const float* __restrict__ sintab, ushort* __restrict__ out,
                                                  float qs) {
    int t = blockIdx.x * 256 + threadIdx.x;   // BATCH*nh*CTX*64
    int j = t & 63;
    int rest = t >> 6;
    int pos = rest & (CTX - 1);
    int rest2 = rest >> 11;
    int hh = rest2 % nh;
    int b = rest2 / nh;
    const float* base = qkv + (size_t)(b * CTX + pos) * ld + co + hh * HD;
    float a = base[j];
    float bb = base[j + 64];
    float sv = sintab[pos * 64 + j] * qs;
    ushort* ob = out + ((size_t)((b * nh + hh) * CTX + pos)) * HD;
    ob[j]      = f2bf((a - bb) * sv);
    ob[j + 64] = f2bf((bb + a) * sv);
}

// ---------- GEMM: C[M][N] (f32) = A[M][K] (bf16) x Bt[N][K] (bf16), optional bias ----------
__global__ __launch_bounds__(256) void k_gemm_bt(const ushort* __restrict__ A, const ushort* __restrict__ Bt,
                                                 float* __restrict__ C, int M, int N, int K,
                                                 const float* __restrict__ bias) {
    __shared__ __align__(16) ushort As[128 * 32];
    __shared__ __align__(16) ushort Bs[128 * 32];
    int tid = threadIdx.x;
    int lane = tid & 63;
    int wave = tid >> 6;
    int wr = wave >> 1, wc = wave & 1;
    int m0 = blockIdx.y * 128, n0 = blockIdx.x * 128;
    int lr = lane & 15, lg = lane >> 4;

    f32x4 acc[4][4] = {};

    int arow = lane >> 2;        // 0..15 within chunk
    int kpart = (lane & 3) * 8;  // 0,8,16,24

    for (int k0 = 0; k0 < K; k0 += 32) {
        #pragma unroll
        for (int s = 0; s < 2; ++s) {
            int c = wave * 2 + s;
            const ushort* ga = A + (size_t)(m0 + c*16 + arow) * K + k0 + kpart;
            gload_lds16(ga, &As[c * 512]);
            const ushort* gb = Bt + (size_t)(n0 + c*16 + arow) * K + k0 + kpart;
            gload_lds16(gb, &Bs[c * 512]);
        }
        __syncthreads();
        bf16x8 af[4], bfr[4];
        #pragma unroll
        for (int mt = 0; mt < 4; ++mt)
            af[mt] = *(const bf16x8*)&As[(wr*64 + mt*16 + lr) * 32 + lg * 8];
        #pragma unroll
        for (int nt = 0; nt < 4; ++nt)
            bfr[nt] = *(const bf16x8*)&Bs[(wc*64 + nt*16 + lr) * 32 + lg * 8];
        #pragma unroll
        for (int mt = 0; mt < 4; ++mt)
            #pragma unroll
            for (int nt = 0; nt < 4; ++nt)
                acc[mt][nt] = __builtin_amdgcn_mfma_f32_16x16x32_bf16(af[mt], bfr[nt], acc[mt][nt], 0, 0, 0);
        __syncthreads();
    }

    #pragma unroll
    for (int mt = 0; mt < 4; ++mt) {
        #pragma unroll
        for (int nt = 0; nt < 4; ++nt) {
            int col = n0 + wc*64 + nt*16 + lr;
            float bv = bias ? bias[col] : 0.0f;
            #pragma unroll
            for (int r = 0; r < 4; ++r) {
                int row = m0 + wr*64 + mt*16 + lg*4 + r;
                C[(size_t)row * N + col] = acc[mt][nt][r] + bv;
            }
        }
    }
}

// ---------- flash attention v2: 32 q-rows / wave, swapped QK^T, 8 waves / block ----------
// Qb [B][NH][CTX][HD] (pre-scaled by 1/sqrt(128)*log2(e)), Kb [B][NG][CTX][HD], Vt [B][NG][HD][CTX]
// y [B*CTX][NH*HD] bf16
// Wave W = blockIdx*8+wid handles q-tile t = 63 - (W>>5) of head bh = W&31 -> uniform work per block,
// longest tiles dispatched first.
__global__ __launch_bounds__(512, 2) void k_attn2(const ushort* __restrict__ Qb, const ushort* __restrict__ Kb,
                                                  const ushort* __restrict__ Vt, ushort* __restrict__ y) {
    int lane = threadIdx.x & 63;
    int wid  = threadIdx.x >> 6;
    int W  = blockIdx.x * 8 + wid;
    int t  = 63 - (W >> 5);        // q-tile index, 0..63
    int bh = W & 31;
    int b = bh >> 4, h = bh & 15, g = h >> 2;
    int ln = lane & 31, hi = lane >> 5;
    int q0 = t * 32;

    // Q fragments: B-operand, col = ln = q row, k(hd) = s*16 + hi*8 + e
    const ushort* qrow = Qb + ((size_t)((b*NH + h) * CTX) + q0 + ln) * HD + hi * 8;
    bf16x8 qf[8];
    #pragma unroll
    for (int s = 0; s < 8; ++s) qf[s] = *(const bf16x8*)(qrow + s * 16);

    const ushort* kbase = Kb + (size_t)(b*NG + g) * CTX * HD;
    const ushort* vbase = Vt + (size_t)(b*NG + g) * HD * CTX;

    f32x16 od[4] = {};             // O: row q = (r&3)+8*(r>>2)+4*hi, col d = dt*32+ln
    float m = -1e30f, lsum = 0.0f; // per q = ln (lanes l and l^32 hold same q)

    for (int kv0 = 0; kv0 <= q0; kv0 += 32) {
        // S^T = K_tile . Q_tile^T  (rows = kv, cols = q)
        f32x16 st = {};
        const ushort* kp = kbase + ((size_t)(kv0 + ln)) * HD + hi * 8;
        #pragma unroll
        for (int s = 0; s < 8; ++s) {
            bf16x8 kf = *(const bf16x8*)(kp + s * 16);
            st = __builtin_amdgcn_mfma_f32_32x32x16_bf16(kf, qf[s], st, 0, 0, 0);
        }
        // V fragments for this kv tile (issue loads early)
        bf16x8 vf[8];
        #pragma unroll
        for (int dt = 0; dt < 4; ++dt)
            #pragma unroll
            for (int ks = 0; ks < 2; ++ks)
                vf[dt*2 + ks] = *(const bf16x8*)(vbase + (size_t)(dt*32 + ln) * CTX + kv0 + ks*16 + hi*8);

        // causal mask — only the diagonal tile
        if (kv0 == q0) {
            #pragma unroll
            for (int r = 0; r < 16; ++r) {
                int kl = (r & 3) + 8*(r >> 2) + 4*hi;
                if (kl > ln) st[r] = -1e30f;
            }
        }
        // tile max (in-register + one cross-half exchange)
        float pmax = st[0];
        #pragma unroll
        for (int r = 1; r < 16; ++r) pmax = fmaxf(pmax, st[r]);
        pmax = fmaxf(pmax, __shfl_xor(pmax, 32, 64));

        // defer-max: rescale O only when the running max grows by > 8 (log2 domain)
        if (!__all(pmax <= m + 8.0f)) {
            float mnew = fmaxf(m, pmax);
            float alpha = exp2f(m - mnew);
            lsum *= alpha;
            m = mnew;
            #pragma unroll
            for (int r = 0; r < 16; ++r) {
                float ar = __shfl(alpha, (r & 3) + 8*(r >> 2) + 4*hi, 64);
                #pragma unroll
                for (int dt = 0; dt < 4; ++dt) od[dt][r] *= ar;
            }
        }
        // P = exp2(S - m), row sum
        float p[16];
        float ls = 0.0f;
        #pragma unroll
        for (int r = 0; r < 16; ++r) { p[r] = exp2f(st[r] - m); ls += p[r]; }
        lsum += ls + __shfl_xor(ls, 32, 64);

        // pack P to bf16 pairs and redistribute into PV A-fragment layout
        uint32_t w[8], x[8];
        #pragma unroll
        for (int j = 0; j < 8; ++j) w[j] = packbf(p[2*j], p[2*j + 1]);
        #pragma unroll
        for (int j = 0; j < 8; ++j) x[j] = (uint32_t)__shfl_xor((int)w[j], 32, 64);
        bf16x8 pa0 = hi ? mkfrag(x[2], x[3], w[2], w[3]) : mkfrag(w[0], w[1], x[0], x[1]);
        bf16x8 pa1 = hi ? mkfrag(x[6], x[7], w[6], w[7]) : mkfrag(w[4], w[5], x[4], x[5]);

        // O += P . V  (4 d-tiles x 2 k-halves)
        #pragma unroll
        for (int dt = 0; dt < 4; ++dt) {
            od[dt] = __builtin_amdgcn_mfma_f32_32x32x16_bf16(pa0, vf[dt*2 + 0], od[dt], 0, 0, 0);
            od[dt] = __builtin_amdgcn_mfma_f32_32x32x16_bf16(pa1, vf[dt*2 + 1], od[dt], 0, 0, 0);
        }
    }

    // epilogue: normalize and store bf16
    float inv = 1.0f / lsum;
    #pragma unroll
    for (int r = 0; r < 16; ++r) {
        float ivr = __shfl(inv, (r & 3) + 8*(r >> 2) + 4*hi, 64);
        int row = q0 + (r & 3) + 8*(r >> 2) + 4*hi;
        #pragma unroll
        for (int dt = 0; dt < 4; ++dt) {
            float v = od[dt][r] * ivr;
            y[((size_t)(b*CTX + row)) * (NH*HD) + h*HD + dt*32 + ln] = f2bf(v);
        }
    }
}

// ---------- workspace layout (bytes) ----------
#define SIN_OFF   ((size_t)0)
#define XB_OFF    ((size_t)524288)
#define WT_OFF    ((size_t)17301504)
#define WOT_OFF   ((size_t)29884416)
#define QKV_OFF   ((size_t)38273024)
#define QB_OFF    ((size_t)88604672)
#define KB_OFF    ((size_t)105381888)
#define VT_OFF    ((size_t)109576192)
#define YB_OFF    ((size_t)113770496)

extern "C" void kernel_launch(void* const* d_in, const int* in_sizes, int n_in,
                              void* d_out, int out_size, void* d_ws, size_t ws_size,
                              hipStream_t stream) {
    const float* x  = (const float*)d_in[0];
    const float* Wq = (const float*)d_in[1];
    const float* Wk = (const float*)d_in[2];
    const float* Wv = (const float*)d_in[3];
    const float* Wo = (const float*)d_in[4];
    const float* bo = (const float*)d_in[5];
    float* out = (float*)d_out;
    char* ws = (char*)d_ws;

    float*  sintab = (float*)(ws + SIN_OFF);
    ushort* xb     = (ushort*)(ws + XB_OFF);
    ushort* Wt     = (ushort*)(ws + WT_OFF);
    ushort* Wot    = (ushort*)(ws + WOT_OFF);
    float*  QKVf   = (float*)(ws + QKV_OFF);
    ushort* Qb     = (ushort*)(ws + QB_OFF);
    ushort* Kb     = (ushort*)(ws + KB_OFF);
    ushort* Vt     = (ushort*)(ws + VT_OFF);
    ushort* yb     = (ushort*)(ws + YB_OFF);

    // 1. sin table
    k_sintab<<<512, 256, 0, stream>>>(sintab);
    // 2. x -> bf16
    k_cvt<<<(MROWS * EMB / 4) / 256, 256, 0, stream>>>((const float4*)x, (ushort4*)xb);
    // 3. weight transposes -> bf16 [N][K]
    dim3 tb(32, 8);
    k_transpose_cvt<<<dim3(EMB/32, EMB/32), tb, 0, stream>>>(Wq, EMB, Wt, EMB);
    k_transpose_cvt<<<dim3((NG*HD)/32, EMB/32), tb, 0, stream>>>(Wk, NG*HD, Wt + (size_t)EMB * EMB, EMB);
    k_transpose_cvt<<<dim3((NG*HD)/32, EMB/32), tb, 0, stream>>>(Wv, NG*HD, Wt + (size_t)(EMB + NG*HD) * EMB, EMB);
    k_transpose_cvt<<<dim3(EMB/32, EMB/32), tb, 0, stream>>>(Wo, EMB, Wot, EMB);
    // 4. QKV = x @ [Wq|Wk|Wv]   (f32 out [4096][3072])
    k_gemm_bt<<<dim3(NQK/128, MROWS/128), 256, 0, stream>>>(xb, Wt, QKVf, MROWS, NQK, EMB, nullptr);
    // 5. RoPE + convert Q (scale*log2e folded), K ; transpose-convert V
    const float qscale = 0.08838834764831845f * 1.4426950408889634f;
    k_rope_cvt<<<(BATCH*NH*CTX*64)/256, 256, 0, stream>>>(QKVf, NQK, 0, NH, sintab, Qb, qscale);
    k_rope_cvt<<<(BATCH*NG*CTX*64)/256, 256, 0, stream>>>(QKVf, NQK, EMB, NG, sintab, Kb, 1.0f);
    for (int b = 0; b < BATCH; ++b)
        for (int g = 0; g < NG; ++g) {
            const float* srcv = QKVf + (size_t)b * CTX * NQK + EMB + NG*HD + g*HD;
            ushort* dstv = Vt + (size_t)(b*NG + g) * HD * CTX;
            k_transpose_cvt<<<dim3(HD/32, CTX/32), tb, 0, stream>>>(srcv, NQK, dstv, CTX);
        }
    // 6. attention (256 blocks x 8 waves, uniform work per block)
    k_attn2<<<256, 512, 0, stream>>>(Qb, Kb, Vt, yb);
    // 7. out = y @ Wo + bo
    k_gemm_bt<<<dim3(EMB/128, MROWS/128), 256, 0, stream>>>(yb, Wot, out, MROWS, EMB, EMB, bo);
}